// Round 1
// baseline (701.051 us; speedup 1.0000x reference)
//
#include <hip/hip_runtime.h>
#include <hip/hip_bf16.h>

#define IN_F   2048
#define OUT_F  2048
#define NG     8
#define BATCH  4096
#define KDIM   (IN_F * (NG + 1))   // 18432 = 576 * 32

typedef short bf16x8 __attribute__((ext_vector_type(8)));
typedef float f32x4  __attribute__((ext_vector_type(4)));
typedef __attribute__((address_space(3))) unsigned char       lds_u8;
typedef const __attribute__((address_space(1))) unsigned char glb_u8;

__device__ __forceinline__ float sigmoidf_(float v) {
    return 1.0f / (1.0f + __expf(-v));
}

// round-to-nearest-even f32 -> bf16 (as ushort)
__device__ __forceinline__ unsigned short f2bf(float f) {
    unsigned int u = __builtin_bit_cast(unsigned int, f);
    u = (u + 0x7fffu + ((u >> 16) & 1u)) >> 16;
    return (unsigned short)u;
}

// ---------------------------------------------------------------------------
// Kernel 1: activation prep.  A'[b][k] bf16, K-contiguous.
//   k in [0, 16384): normalized RBF basis, layout i*8+g
//   k in [16384, 18432): x_weighted
// ---------------------------------------------------------------------------
__global__ __launch_bounds__(256) void act_kernel(
    const float* __restrict__ x, const float* __restrict__ fi,
    const float* __restrict__ grid, unsigned short* __restrict__ Abf)
{
    const int idx = blockIdx.x * 256 + threadIdx.x;    // b*2048 + i
    const int b = idx >> 11;
    const int i = idx & (IN_F - 1);

    const float s  = sigmoidf_(fi[i]);
    const float xw = x[idx] * s;
    const float xn = tanhf(xw);

    float e[NG];
    float denom = 0.0f;
#pragma unroll
    for (int g = 0; g < NG; ++g) {
        const float d = xn - grid[g];
        e[g] = __expf(-2.0f * d * d);
        denom += e[g];
    }
    const float rinv = 1.0f / fmaxf(denom, 1e-12f);

    union { unsigned short us[8]; int4 v; } pk;
#pragma unroll
    for (int g = 0; g < NG; ++g) pk.us[g] = f2bf(e[g] * rinv);

    *(int4*)(Abf + (size_t)b * KDIM + i * NG) = pk.v;        // 16B store
    Abf[(size_t)b * KDIM + IN_F * NG + i] = f2bf(xw);
}

// ---------------------------------------------------------------------------
// Kernel 2: weight prep.  W'[o][k] bf16, K-contiguous (B^T layout).
//   k in [0, 16384): gate_o * spline_w[o][i][g]
//   k in [16384, 18432): (1-gate_o) * base_w[o][i]
// ---------------------------------------------------------------------------
__global__ __launch_bounds__(256) void wprep_kernel(
    const float* __restrict__ bw, const float* __restrict__ sw,
    const float* __restrict__ ag, unsigned short* __restrict__ Wbf)
{
    const int idx = blockIdx.x * 256 + threadIdx.x;    // o*2048 + i
    const int o = idx >> 11;
    const int i = idx & (IN_F - 1);

    const float gate = sigmoidf_(ag[o]);

    const float4 s0 = *(const float4*)(sw + (size_t)idx * NG);
    const float4 s1 = *(const float4*)(sw + (size_t)idx * NG + 4);

    union { unsigned short us[8]; int4 v; } pk;
    pk.us[0] = f2bf(gate * s0.x); pk.us[1] = f2bf(gate * s0.y);
    pk.us[2] = f2bf(gate * s0.z); pk.us[3] = f2bf(gate * s0.w);
    pk.us[4] = f2bf(gate * s1.x); pk.us[5] = f2bf(gate * s1.y);
    pk.us[6] = f2bf(gate * s1.z); pk.us[7] = f2bf(gate * s1.w);

    *(int4*)(Wbf + (size_t)o * KDIM + i * NG) = pk.v;        // 16B store
    Wbf[(size_t)o * KDIM + IN_F * NG + i] = f2bf((1.0f - gate) * bw[idx]);
}

// ---------------------------------------------------------------------------
// Kernel 3: bf16 GEMM, m97 structure. C[4096][2048] f32 = A'[4096][K] * W'[2048][K]^T
// 128x128 tile, BK=32, 4 waves (2x2), 4x4 16x16x32 MFMA frags per wave,
// global_load_lds width 16, double-buffered LDS, 1 barrier per K-step.
// Epilogue adds (1-gate_o)*base_b[o].
// ---------------------------------------------------------------------------
__global__ __launch_bounds__(256, 2) void gemm_kernel(
    const unsigned short* __restrict__ A, const unsigned short* __restrict__ B,
    const float* __restrict__ bb, const float* __restrict__ ag,
    float* __restrict__ C)
{
    __shared__ __align__(16) unsigned char lds[2][2][8192];  // [buf][A,B][128 rows x 32 k x bf16]

    const int tid = threadIdx.x;
    const int bid = blockIdx.x;
    // XCD-bijective swizzle: 512 wgs, 8 XCDs, 64 contiguous wgs per XCD
    const int swz = ((bid & 7) << 6) + (bid >> 3);
    const int bm = swz >> 4;        // 0..31
    const int bn = swz & 15;        // 0..15

    const int lane = tid & 63, wid = tid >> 6;
    const int wm = wid >> 1, wn = wid & 1;
    const int fr = lane & 15;       // row-in-frag (A) / col-in-frag (B)
    const int kg = lane >> 4;       // k-group 0..3

    // staging: element e (0..511) covers LDS bytes e*16; row = e>>2, k-blk = e&3
    const int e0 = tid, e1 = tid + 256;
    const unsigned short* aS0 = A + (size_t)(bm * 128 + (e0 >> 2)) * KDIM + (e0 & 3) * 8;
    const unsigned short* aS1 = A + (size_t)(bm * 128 + (e1 >> 2)) * KDIM + (e1 & 3) * 8;
    const unsigned short* bS0 = B + (size_t)(bn * 128 + (e0 >> 2)) * KDIM + (e0 & 3) * 8;
    const unsigned short* bS1 = B + (size_t)(bn * 128 + (e1 >> 2)) * KDIM + (e1 & 3) * 8;

    f32x4 acc[4][4] = {};

    auto stage = [&](int buf, int kt) {
        const int ko = kt * 32;
        __builtin_amdgcn_global_load_lds((glb_u8*)(aS0 + ko),
            (lds_u8*)(&lds[buf][0][0]) + e0 * 16, 16, 0, 0);
        __builtin_amdgcn_global_load_lds((glb_u8*)(aS1 + ko),
            (lds_u8*)(&lds[buf][0][0]) + e1 * 16, 16, 0, 0);
        __builtin_amdgcn_global_load_lds((glb_u8*)(bS0 + ko),
            (lds_u8*)(&lds[buf][1][0]) + e0 * 16, 16, 0, 0);
        __builtin_amdgcn_global_load_lds((glb_u8*)(bS1 + ko),
            (lds_u8*)(&lds[buf][1][0]) + e1 * 16, 16, 0, 0);
    };

    stage(0, 0);

    const int NT = KDIM / 32;   // 576
#pragma unroll 2
    for (int kt = 0; kt < NT; ++kt) {
        __syncthreads();                    // drains vmcnt -> buf[cur] ready
        const int cur = kt & 1;
        if (kt + 1 < NT) stage(cur ^ 1, kt + 1);

        const unsigned char* La = &lds[cur][0][0];
        const unsigned char* Lb = &lds[cur][1][0];
        bf16x8 af[4], bfr[4];
#pragma unroll
        for (int m = 0; m < 4; ++m)
            af[m] = *(const bf16x8*)(La + ((wm * 64 + m * 16 + fr) * 64 + kg * 16));
#pragma unroll
        for (int n = 0; n < 4; ++n)
            bfr[n] = *(const bf16x8*)(Lb + ((wn * 64 + n * 16 + fr) * 64 + kg * 16));
#pragma unroll
        for (int m = 0; m < 4; ++m)
#pragma unroll
            for (int n = 0; n < 4; ++n)
                acc[m][n] = __builtin_amdgcn_mfma_f32_16x16x32_bf16(
                    af[m], bfr[n], acc[m][n], 0, 0, 0);
    }

    // epilogue: C/D layout col=lane&15, row=(lane>>4)*4+reg  [m89 verified]
    const int colbase = bn * 128 + wn * 64;
    const int rowbase = bm * 128 + wm * 64;
#pragma unroll
    for (int n = 0; n < 4; ++n) {
        const int col = colbase + n * 16 + fr;
        const float gate = sigmoidf_(ag[col]);
        const float bias = (1.0f - gate) * bb[col];
#pragma unroll
        for (int m = 0; m < 4; ++m) {
            const int r0 = rowbase + m * 16 + kg * 4;
#pragma unroll
            for (int j = 0; j < 4; ++j)
                C[(size_t)(r0 + j) * OUT_F + col] = acc[m][n][j] + bias;
        }
    }
}

// ---------------------------------------------------------------------------
extern "C" void kernel_launch(void* const* d_in, const int* in_sizes, int n_in,
                              void* d_out, int out_size, void* d_ws, size_t ws_size,
                              hipStream_t stream)
{
    const float* x  = (const float*)d_in[0];   // [4096,2048]
    const float* bw = (const float*)d_in[1];   // [2048,2048]
    const float* bb = (const float*)d_in[2];   // [2048]
    const float* sw = (const float*)d_in[3];   // [2048,2048,8]
    const float* gr = (const float*)d_in[4];   // [8]
    const float* ag = (const float*)d_in[5];   // [2048]
    const float* fi = (const float*)d_in[6];   // [2048]
    float* out = (float*)d_out;                // [4096,2048] f32

    unsigned short* Abf = (unsigned short*)d_ws;             // [4096][18432] bf16
    unsigned short* Wbf = Abf + (size_t)BATCH * KDIM;        // [2048][18432] bf16

    const size_t need = ((size_t)BATCH + OUT_F) * KDIM * sizeof(unsigned short);
    if (ws_size < need) return;  // fail visibly rather than corrupt memory

    act_kernel<<<BATCH * IN_F / 256, 256, 0, stream>>>(x, fi, gr, Abf);
    wprep_kernel<<<OUT_F * IN_F / 256, 256, 0, stream>>>(bw, sw, ag, Wbf);
    gemm_kernel<<<512, 256, 0, stream>>>(Abf, Wbf, bb, ag, out);
}

// Round 2
// 551.084 us; speedup vs baseline: 1.2721x; 1.2721x over previous
//
#include <hip/hip_runtime.h>
#include <hip/hip_bf16.h>

#define IN_F   2048
#define OUT_F  2048
#define NG     8
#define BATCH  4096
#define KDIM   (IN_F * (NG + 1))   // 18432
#define BK     64
#define NT     (KDIM / BK)         // 288
#define BM     256
#define BN     128
#define ASZ    (BM * BK * 2)       // 32768 B
#define BSZ    (BN * BK * 2)       // 16384 B
#define BUFSZ  (ASZ + BSZ)         // 49152 B

typedef short bf16x8 __attribute__((ext_vector_type(8)));
typedef float f32x4  __attribute__((ext_vector_type(4)));
typedef __attribute__((address_space(3))) unsigned char       lds_u8;
typedef const __attribute__((address_space(1))) unsigned char glb_u8;

__device__ __forceinline__ float sigmoidf_(float v) {
    return 1.0f / (1.0f + __expf(-v));
}

// round-to-nearest-even f32 -> bf16 (as ushort)
__device__ __forceinline__ unsigned short f2bf(float f) {
    unsigned int u = __builtin_bit_cast(unsigned int, f);
    u = (u + 0x7fffu + ((u >> 16) & 1u)) >> 16;
    return (unsigned short)u;
}

// ---------------------------------------------------------------------------
// Kernel 1: activation prep.  A'[b][k] bf16, K-contiguous.
//   k in [0,16384): L1-normalized RBF basis (i*8+g); [16384,18432): x_weighted
// 4 items/thread, block covers 1024 consecutive idx (one b per block).
// ---------------------------------------------------------------------------
__global__ __launch_bounds__(256) void act_kernel(
    const float* __restrict__ x, const float* __restrict__ fi,
    const float* __restrict__ gr, unsigned short* __restrict__ Abf)
{
    const int base = blockIdx.x * 1024;
    const int tid  = threadIdx.x;
    const int b    = base >> 11;                    // uniform per block
    const float4 g0 = *(const float4*)gr;
    const float4 g1 = *(const float4*)(gr + 4);
    unsigned short* rowp = Abf + (size_t)b * KDIM;

#pragma unroll
    for (int e = 0; e < 4; ++e) {
        const int idx = base + tid + e * 256;
        const int i   = idx & (IN_F - 1);
        const float s  = sigmoidf_(fi[i]);
        const float xw = x[idx] * s;
        // tanh via exp: (e^{2x}-1)/(e^{2x}+1)
        const float ex = __expf(2.0f * xw);
        const float xn = (ex - 1.0f) / (ex + 1.0f);

        float ev[NG];
        float d;
        d = xn - g0.x; ev[0] = __expf(-2.0f * d * d);
        d = xn - g0.y; ev[1] = __expf(-2.0f * d * d);
        d = xn - g0.z; ev[2] = __expf(-2.0f * d * d);
        d = xn - g0.w; ev[3] = __expf(-2.0f * d * d);
        d = xn - g1.x; ev[4] = __expf(-2.0f * d * d);
        d = xn - g1.y; ev[5] = __expf(-2.0f * d * d);
        d = xn - g1.z; ev[6] = __expf(-2.0f * d * d);
        d = xn - g1.w; ev[7] = __expf(-2.0f * d * d);
        float denom = ((ev[0] + ev[1]) + (ev[2] + ev[3])) +
                      ((ev[4] + ev[5]) + (ev[6] + ev[7]));
        const float rinv = 1.0f / fmaxf(denom, 1e-12f);

        union { unsigned short us[8]; int4 v; } pk;
#pragma unroll
        for (int g = 0; g < NG; ++g) pk.us[g] = f2bf(ev[g] * rinv);
        *(int4*)(rowp + i * NG) = pk.v;             // 16B coalesced
        rowp[IN_F * NG + i] = f2bf(xw);             // 2B coalesced
    }
}

// ---------------------------------------------------------------------------
// Kernel 2: weight prep.  W'[o][k] bf16, K-contiguous (B^T layout).
//   k in [0,16384): gate*spline_w; [16384,18432): (1-gate)*base_w
// ---------------------------------------------------------------------------
__global__ __launch_bounds__(256) void wprep_kernel(
    const float* __restrict__ bw, const float* __restrict__ sw,
    const float* __restrict__ ag, unsigned short* __restrict__ Wbf)
{
    const int base = blockIdx.x * 1024;
    const int tid  = threadIdx.x;
    const int o    = base >> 11;                    // uniform per block
    const float gate = sigmoidf_(ag[o]);
    const float og   = 1.0f - gate;
    unsigned short* rowp = Wbf + (size_t)o * KDIM;

#pragma unroll
    for (int e = 0; e < 4; ++e) {
        const int idx = base + tid + e * 256;
        const int i   = idx & (IN_F - 1);
        const float4 s0 = *(const float4*)(sw + (size_t)idx * NG);
        const float4 s1 = *(const float4*)(sw + (size_t)idx * NG + 4);
        union { unsigned short us[8]; int4 v; } pk;
        pk.us[0] = f2bf(gate * s0.x); pk.us[1] = f2bf(gate * s0.y);
        pk.us[2] = f2bf(gate * s0.z); pk.us[3] = f2bf(gate * s0.w);
        pk.us[4] = f2bf(gate * s1.x); pk.us[5] = f2bf(gate * s1.y);
        pk.us[6] = f2bf(gate * s1.z); pk.us[7] = f2bf(gate * s1.w);
        *(int4*)(rowp + i * NG) = pk.v;
        rowp[IN_F * NG + i] = f2bf(og * bw[idx]);
    }
}

// ---------------------------------------------------------------------------
// Kernel 3: bf16 GEMM, 8-phase-style deep pipeline.
// C[4096][2048] = A'[4096][K] * W'[2048][K]^T, K=18432.
// BM=256 BN=128 BK=64, 8 waves (4M x 2N, per-wave 64x64), 3 LDS buffers
// (lookahead 2 K-tiles), counted vmcnt(6) once per K-tile, T2 XOR swizzle
// (both-sides: pre-swizzled global source + swizzled ds_read), T5 setprio.
// ---------------------------------------------------------------------------
#define MFMA(d, a, b) d = __builtin_amdgcn_mfma_f32_16x16x32_bf16(a, b, d, 0, 0, 0)

#define MFMA8(m0i, m1i, va0, va1)                              \
    __builtin_amdgcn_s_setprio(1);                             \
    MFMA(acc[m0i][0], va0, vb0); MFMA(acc[m0i][1], va0, vb1);  \
    MFMA(acc[m0i][2], va0, vb2); MFMA(acc[m0i][3], va0, vb3);  \
    MFMA(acc[m1i][0], va1, vb0); MFMA(acc[m1i][1], va1, vb1);  \
    MFMA(acc[m1i][2], va1, vb2); MFMA(acc[m1i][3], va1, vb3);  \
    __builtin_amdgcn_s_setprio(0);

#define PHASE_MID()                                            \
    __builtin_amdgcn_sched_barrier(0);                         \
    __builtin_amdgcn_s_barrier();                              \
    asm volatile("s_waitcnt lgkmcnt(0)" ::: "memory");         \
    __builtin_amdgcn_sched_barrier(0);

#define PHASE_END()                                            \
    __builtin_amdgcn_sched_barrier(0);                         \
    __builtin_amdgcn_s_barrier();

// ds_read with T2 swizzle: byte = r*128 + ((kg ^ (r&7)) ^ (kk<<2))*16
#define LDA(kk, m) (*(const bf16x8*)(lds + curBase + (oA##m ^ ((kk) << 6))))
#define LDB(kk, n) (*(const bf16x8*)(lds + curBase + (oB##n ^ ((kk) << 6))))

// staging: linear LDS dest (lane x 16B), inverse-swizzled global source
#define GLA(j) __builtin_amdgcn_global_load_lds((glb_u8*)(aS##j + ko), \
                   (lds_u8*)(lds + stBase + aO##j), 16, 0, 0)
#define GLB(j) __builtin_amdgcn_global_load_lds((glb_u8*)(bS##j + ko), \
                   (lds_u8*)(lds + stBase + bO##j), 16, 0, 0)

__global__ __launch_bounds__(512, 2) void gemm_kernel(
    const unsigned short* __restrict__ A, const unsigned short* __restrict__ B,
    const float* __restrict__ bb, const float* __restrict__ ag,
    float* __restrict__ C)
{
    __shared__ __align__(16) unsigned char lds[3 * BUFSZ];   // 144 KiB

    const int tid = threadIdx.x;
    const int bid = blockIdx.x;
    // 256 WGs, 8 XCDs -> 32 contiguous tiles per XCD (bijective)
    const int swz = ((bid & 7) << 5) + (bid >> 3);
    const int bm = swz >> 4, bn = swz & 15;

    const int lane = tid & 63, wid = tid >> 6;
    const int wm = wid >> 1, wn = wid & 1;
    const int fr = lane & 15, kg = lane >> 4;

    // ---- staging source pointers (pre-swizzled chunk) + LDS byte offsets
    // A: 2048 elements of 16B -> 4/thread; B: 1024 -> 2/thread
#define MKSA(j)                                                         \
    const int eA##j = tid + (j) * 512;                                  \
    const int rA_##j = eA##j >> 3, cA_##j = (eA##j & 7) ^ (rA_##j & 7); \
    const unsigned short* aS##j = A + (size_t)(bm * BM + rA_##j) * KDIM + cA_##j * 8; \
    const int aO##j = eA##j * 16;
    MKSA(0) MKSA(1) MKSA(2) MKSA(3)
#define MKSB(j)                                                         \
    const int eB##j = tid + (j) * 512;                                  \
    const int rB_##j = eB##j >> 3, cB_##j = (eB##j & 7) ^ (rB_##j & 7); \
    const unsigned short* bS##j = B + (size_t)(bn * BN + rB_##j) * KDIM + cB_##j * 8; \
    const int bO##j = ASZ + eB##j * 16;
    MKSB(0) MKSB(1)

    // ---- ds_read base offsets (kk=0), XOR kk<<6 selects k-half
#define MKOA(m)                                                \
    const int rAm##m = wm * 64 + (m) * 16 + fr;                \
    const int oA##m = rAm##m * 128 + ((kg ^ (rAm##m & 7)) << 4);
    MKOA(0) MKOA(1) MKOA(2) MKOA(3)
#define MKOB(n)                                                \
    const int rBn##n = wn * 64 + (n) * 16 + fr;                \
    const int oB##n = ASZ + rBn##n * 128 + ((kg ^ (rBn##n & 7)) << 4);
    MKOB(0) MKOB(1) MKOB(2) MKOB(3)

    f32x4 acc[4][4] = {};

    // ---- prologue: stage tiles 0 and 1, wait for tile 0 (vmcnt(6))
    {
        const int stBase = 0; const long ko = 0;
        GLA(0); GLA(1); GLA(2); GLA(3); GLB(0); GLB(1);
    }
    {
        const int stBase = BUFSZ; const long ko = BK;
        GLA(0); GLA(1); GLA(2); GLA(3); GLB(0); GLB(1);
    }
    asm volatile("s_waitcnt vmcnt(6)" ::: "memory");
    __builtin_amdgcn_sched_barrier(0);
    __builtin_amdgcn_s_barrier();

    int curBase = 0;
    for (int t = 0; t < NT; ++t) {
        const int stBase = (curBase >= BUFSZ) ? (curBase - BUFSZ)
                                              : (curBase + 2 * BUFSZ);
        const bool doSt = (t + 2) < NT;
        const long ko = (long)(t + 2) * BK;

        // phase 0: kk0, rows m0,m1; stage A j0,j1
        bf16x8 vb0 = LDB(0, 0), vb1 = LDB(0, 1), vb2 = LDB(0, 2), vb3 = LDB(0, 3);
        bf16x8 va0 = LDA(0, 0), va1 = LDA(0, 1);
        if (doSt) { GLA(0); GLA(1); }
        PHASE_MID(); MFMA8(0, 1, va0, va1); PHASE_END();

        // phase 1: kk0, rows m2,m3 (vb reused); stage A j2,j3
        va0 = LDA(0, 2); va1 = LDA(0, 3);
        if (doSt) { GLA(2); GLA(3); }
        PHASE_MID(); MFMA8(2, 3, va0, va1); PHASE_END();

        // phase 2: kk1, rows m0,m1; stage B j0,j1
        vb0 = LDB(1, 0); vb1 = LDB(1, 1); vb2 = LDB(1, 2); vb3 = LDB(1, 3);
        va0 = LDA(1, 0); va1 = LDA(1, 1);
        if (doSt) { GLB(0); GLB(1); }
        PHASE_MID(); MFMA8(0, 1, va0, va1); PHASE_END();

        // phase 3: kk1, rows m2,m3; tile-boundary counted wait
        va0 = LDA(1, 2); va1 = LDA(1, 3);
        PHASE_MID(); MFMA8(2, 3, va0, va1);
        if (t < NT - 2) { asm volatile("s_waitcnt vmcnt(6)" ::: "memory"); }
        else            { asm volatile("s_waitcnt vmcnt(0)" ::: "memory"); }
        PHASE_END();

        curBase = (curBase == 2 * BUFSZ) ? 0 : (curBase + BUFSZ);
    }

    // ---- epilogue: C/D layout col=lane&15, row=kg*4+j [m89 verified]
    const int colb = bn * BN + wn * 64;
    const int rowb = bm * BM + wm * 64;
#pragma unroll
    for (int n = 0; n < 4; ++n) {
        const int col = colb + n * 16 + fr;
        const float gate = sigmoidf_(ag[col]);
        const float bias = (1.0f - gate) * bb[col];
#pragma unroll
        for (int m = 0; m < 4; ++m) {
            const int r0 = rowb + m * 16 + kg * 4;
#pragma unroll
            for (int j = 0; j < 4; ++j)
                C[(size_t)(r0 + j) * OUT_F + col] = acc[m][n][j] + bias;
        }
    }
}

// ---------------------------------------------------------------------------
extern "C" void kernel_launch(void* const* d_in, const int* in_sizes, int n_in,
                              void* d_out, int out_size, void* d_ws, size_t ws_size,
                              hipStream_t stream)
{
    const float* x  = (const float*)d_in[0];   // [4096,2048]
    const float* bw = (const float*)d_in[1];   // [2048,2048]
    const float* bb = (const float*)d_in[2];   // [2048]
    const float* sw = (const float*)d_in[3];   // [2048,2048,8]
    const float* gr = (const float*)d_in[4];   // [8]
    const float* ag = (const float*)d_in[5];   // [2048]
    const float* fi = (const float*)d_in[6];   // [2048]
    float* out = (float*)d_out;                // [4096,2048] f32

    unsigned short* Abf = (unsigned short*)d_ws;             // [4096][18432] bf16
    unsigned short* Wbf = Abf + (size_t)BATCH * KDIM;        // [2048][18432] bf16

    const size_t need = ((size_t)BATCH + OUT_F) * KDIM * sizeof(unsigned short);
    if (ws_size < need) return;

    act_kernel<<<BATCH * IN_F / 1024, 256, 0, stream>>>(x, fi, gr, Abf);
    wprep_kernel<<<OUT_F * IN_F / 1024, 256, 0, stream>>>(bw, sw, ag, Wbf);
    gemm_kernel<<<(BATCH / BM) * (OUT_F / BN), 512, 0, stream>>>(Abf, Wbf, bb, ag, out);
}